// Round 1
// baseline (2762.110 us; speedup 1.0000x reference)
//
#include <hip/hip_runtime.h>
#include <hip/hip_bf16.h>
#include <math.h>

#define B_ 16
#define L_ 2048
#define H_ 1024
#define A_ 1024
#define C_ 5

#define R_ 16            // rows per tile in probs kernel
#define ASPLIT 4         // a-dimension split in probs kernel
#define TILES (L_ / R_)  // 128
#define CS 64            // rows per chunk in segment-sum kernel
#define NCHUNK (L_ / CS) // 32

// ---- workspace layout (bytes) ----
// [OFF_SCAL]   2 floats: denom = sqrt(A*qvar), wsum = sum(W_cls)
// [OFF_END]    B ints:   end[b] = sum(attn row)
// [OFF_CNT]    B ints:   cnt[b] = # masked (attn==0) positions
// [OFF_STARTS] B*C ints: sorted mlm marker positions
// [OFF_MZ]     2*B floats: m[b], Z[b] (softmax max / denominator)
// [OFF_LIST]   B*L ints: compacted masked position list per batch
// [OFF_PP]     ASPLIT*B*L floats: partial probs (per a-slice)
// [OFF_PROBS]  B*L floats: final probs (masked entries only)
// [OFF_SEG]    B*C*NCHUNK floats: segment-chunk partial dot sums
// [OFF_ATT]    B*C*NCHUNK floats: segment-chunk partial att sums
static constexpr size_t OFF_SCAL   = 0;
static constexpr size_t OFF_END    = 64;
static constexpr size_t OFF_CNT    = 192;
static constexpr size_t OFF_STARTS = 320;
static constexpr size_t OFF_MZ     = 1024;
static constexpr size_t OFF_LIST   = 4096;
static constexpr size_t OFF_PP     = OFF_LIST + (size_t)B_ * L_ * 4;          // 135168
static constexpr size_t OFF_PROBS  = OFF_PP + (size_t)ASPLIT * B_ * L_ * 4;   // 659456
static constexpr size_t OFF_SEG    = OFF_PROBS + (size_t)B_ * L_ * 4;         // 790528
static constexpr size_t OFF_ATT    = OFF_SEG + (size_t)B_ * C_ * NCHUNK * 4;  // 800768

// ---------------- kernel A: masks -> {end, cnt, list, starts}; scalars ----------------
__global__ __launch_bounds__(256) void kA(const int* __restrict__ attn,
                                          const int* __restrict__ mlm,
                                          const float* __restrict__ query,
                                          const float* __restrict__ Wcls,
                                          float* __restrict__ ws_scal,
                                          int* __restrict__ endv,
                                          int* __restrict__ cnt,
                                          int* __restrict__ starts,
                                          int* __restrict__ list) {
  __shared__ int   scn[256];
  __shared__ float sfA[256];
  __shared__ float sfB[256];
  const int b = blockIdx.x;
  const int t = threadIdx.x;

  if (b < B_) {
    const int* arow = attn + (size_t)b * L_;
    const int* mrow = mlm + (size_t)b * L_;
    const int base = t * 8;

    // ---- masked (attn==0) compaction, ascending order ----
    int loc[8];
    int lc = 0;
    for (int j = 0; j < 8; ++j) {
      int l = base + j;
      if (arow[l] == 0) loc[lc++] = l;
    }
    scn[t] = lc;
    __syncthreads();
    for (int off = 1; off < 256; off <<= 1) {
      int v = (t >= off) ? scn[t - off] : 0;
      __syncthreads();
      scn[t] += v;
      __syncthreads();
    }
    int excl = scn[t] - lc;
    int total = scn[255];
    int* lrow = list + (size_t)b * L_;
    for (int j = 0; j < lc; ++j) lrow[excl + j] = loc[j];
    if (t == 0) {
      cnt[b] = total;
      endv[b] = L_ - total;  // attn is {0,1}
    }
    __syncthreads();

    // ---- mlm marker compaction (exactly C markers per row) ----
    int mloc[8];
    int mc = 0;
    for (int j = 0; j < 8; ++j) {
      int l = base + j;
      if (mrow[l] > 0) mloc[mc++] = l;
    }
    scn[t] = mc;
    __syncthreads();
    for (int off = 1; off < 256; off <<= 1) {
      int v = (t >= off) ? scn[t - off] : 0;
      __syncthreads();
      scn[t] += v;
      __syncthreads();
    }
    int mexcl = scn[t] - mc;
    for (int j = 0; j < mc; ++j) {
      int idx = mexcl + j;
      if (idx < C_) starts[b * C_ + idx] = mloc[j];
    }
  } else {
    // ---- scalars: qvar (ddof=1) -> denom, wsum ----
    float s = 0.f, s2 = 0.f;
    for (int i = t; i < A_; i += 256) {
      float q = query[i];
      s += q;
      s2 = fmaf(q, q, s2);
    }
    sfA[t] = s;
    sfB[t] = s2;
    __syncthreads();
    for (int off = 128; off >= 1; off >>= 1) {
      if (t < off) {
        sfA[t] += sfA[t + off];
        sfB[t] += sfB[t + off];
      }
      __syncthreads();
    }
    float qsum = sfA[0], qsq = sfB[0];
    __syncthreads();
    float w = 0.f;
    for (int i = t; i < H_; i += 256) w += Wcls[i];
    sfA[t] = w;
    __syncthreads();
    for (int off = 128; off >= 1; off >>= 1) {
      if (t < off) sfA[t] += sfA[t + off];
      __syncthreads();
    }
    if (t == 0) {
      float var = (qsq - qsum * qsum / (float)A_) / (float)(A_ - 1);
      ws_scal[0] = sqrtf((float)A_ * var);  // denom
      ws_scal[1] = sfA[0];                  // wsum
    }
  }
}

// ---------------- kernel C: probs partials for masked rows ----------------
// block handles R_ masked rows x (A_/ASPLIT) attention units
__global__ __launch_bounds__(256) void kC(const float* __restrict__ inp,
                                          const float* __restrict__ Wh,
                                          const float* __restrict__ bh,
                                          const float* __restrict__ query,
                                          const int* __restrict__ cnt,
                                          const int* __restrict__ list,
                                          float* __restrict__ probpart) {
  const int bid = blockIdx.x;
  const int as = bid % ASPLIT;
  const int tile = (bid / ASPLIT) % TILES;
  const int b = bid / (ASPLIT * TILES);
  const int c0 = cnt[b];
  const int base = tile * R_;
  if (base >= c0) return;
  const int n = (c0 - base < R_) ? (c0 - base) : R_;

  __shared__ float sm[R_][H_];  // 64 KiB exactly
  const int t = threadIdx.x;

  // stage rows into LDS (coalesced float4)
  for (int r = 0; r < R_; ++r) {
    float4 v = make_float4(0.f, 0.f, 0.f, 0.f);
    if (r < n) {
      int l = list[(size_t)b * L_ + base + r];
      v = *(const float4*)(inp + ((size_t)(b * L_ + l)) * H_ + 4 * t);
    }
    *(float4*)(&sm[r][4 * t]) = v;
  }
  __syncthreads();

  const int alane = t & 15;  // a-lane within slice
  const int r = t >> 4;      // row index
  const int abase = as * (A_ / ASPLIT) + alane;  // a = abase + 16*k

  float acc[16];
#pragma unroll
  for (int k = 0; k < 16; ++k) acc[k] = bh[abase + 16 * k];

  const float4* W4 = (const float4*)Wh;
  const float4* S4 = (const float4*)(&sm[r][0]);
#pragma unroll 4
  for (int h4 = 0; h4 < H_ / 4; ++h4) {
    float4 x = S4[h4];
#pragma unroll
    for (int k = 0; k < 16; ++k) {
      float4 w = W4[(size_t)(abase + 16 * k) * (H_ / 4) + h4];
      acc[k] = fmaf(x.x, w.x, acc[k]);
      acc[k] = fmaf(x.y, w.y, acc[k]);
      acc[k] = fmaf(x.z, w.z, acc[k]);
      acc[k] = fmaf(x.w, w.w, acc[k]);
    }
  }

  float part = 0.f;
#pragma unroll
  for (int k = 0; k < 16; ++k) {
    int a = abase + 16 * k;
    part = fmaf(tanhf(acc[k]), query[a], part);
  }
  // reduce across the 16 a-lanes of this row (lanes are consecutive in-wave)
  for (int off = 1; off < 16; off <<= 1) part += __shfl_xor(part, off, 64);

  if (alane == 0 && r < n) {
    int l = list[(size_t)b * L_ + base + r];
    probpart[((size_t)as * B_ + b) * L_ + l] = part;
  }
}

// ---------------- kernel D: finalize probs, per-batch softmax scalars ----------------
__global__ __launch_bounds__(256) void kD(const int* __restrict__ attn,
                                          const int* __restrict__ cnt,
                                          const int* __restrict__ list,
                                          const float* __restrict__ probpart,
                                          const float* __restrict__ ws_scal,
                                          float* __restrict__ probs,
                                          float* __restrict__ mZ) {
  __shared__ float sred[256];
  const int b = blockIdx.x;
  const int t = threadIdx.x;
  const float denom = ws_scal[0];
  const int c0 = cnt[b];

  for (int i = t; i < c0; i += 256) {
    int l = list[(size_t)b * L_ + i];
    float s = 0.f;
    for (int as = 0; as < ASPLIT; ++as) s += probpart[((size_t)as * B_ + b) * L_ + l];
    probs[(size_t)b * L_ + l] = s / denom;
  }
  __syncthreads();

  const int* arow = attn + (size_t)b * L_;
  float mx = -1e30f;
  for (int l = t; l < L_; l += 256) {
    float lg = 0.f;
    if (arow[l] == 0) lg = -1000.0f * probs[(size_t)b * L_ + l];
    mx = fmaxf(mx, lg);
  }
  sred[t] = mx;
  __syncthreads();
  for (int off = 128; off >= 1; off >>= 1) {
    if (t < off) sred[t] = fmaxf(sred[t], sred[t + off]);
    __syncthreads();
  }
  const float m = sred[0];
  __syncthreads();

  float zs = 0.f;
  for (int l = t; l < L_; l += 256) {
    float lg = 0.f;
    if (arow[l] == 0) lg = -1000.0f * probs[(size_t)b * L_ + l];
    zs += expf(lg - m);
  }
  sred[t] = zs;
  __syncthreads();
  for (int off = 128; off >= 1; off >>= 1) {
    if (t < off) sred[t] += sred[t + off];
    __syncthreads();
  }
  if (t == 0) {
    mZ[b] = m;
    mZ[B_ + b] = sred[0];
  }
}

// ---------------- kernel E: segment chunk sums ----------------
// logits contribution: dot(sum_rows(input), W_cls) + att sums
__global__ __launch_bounds__(256) void kE(const float* __restrict__ inp,
                                          const int* __restrict__ attn,
                                          const float* __restrict__ probs,
                                          const int* __restrict__ starts,
                                          const int* __restrict__ endv,
                                          const float* __restrict__ mZ,
                                          const float* __restrict__ Wcls,
                                          float* __restrict__ segpart,
                                          float* __restrict__ attpart) {
  __shared__ float s1[256];
  __shared__ float s2[256];
  const int bid = blockIdx.x;
  const int k = bid % NCHUNK;
  const int c = (bid / NCHUNK) % C_;
  const int b = bid / (NCHUNK * C_);
  const int t = threadIdx.x;

  const int st = starts[b * C_ + c];
  const int bound = (c < C_ - 1) ? (starts[b * C_ + c + 1] - 1) : (endv[b] - 1);
  int lo = st + 1 + k * CS;
  int hi = st + 1 + (k + 1) * CS;
  if (bound < hi) hi = bound;

  const float m = mZ[b];
  const float Z = mZ[B_ + b];

  float4 vacc = make_float4(0.f, 0.f, 0.f, 0.f);
  float attacc = 0.f;
  if (lo < hi) {
    for (int l = lo; l < hi; ++l) {
      const float4* row = (const float4*)(inp + ((size_t)(b * L_ + l)) * H_);
      float4 v = row[t];
      vacc.x += v.x; vacc.y += v.y; vacc.z += v.z; vacc.w += v.w;
    }
    for (int l = lo + t; l < hi; l += 256) {
      float lg = 0.f;
      if (attn[(size_t)b * L_ + l] == 0) lg = -1000.0f * probs[(size_t)b * L_ + l];
      attacc += expf(lg - m) / Z;
    }
  }
  float pd = vacc.x * Wcls[4 * t] + vacc.y * Wcls[4 * t + 1] +
             vacc.z * Wcls[4 * t + 2] + vacc.w * Wcls[4 * t + 3];
  s1[t] = pd;
  s2[t] = attacc;
  __syncthreads();
  for (int off = 128; off >= 1; off >>= 1) {
    if (t < off) {
      s1[t] += s1[t + off];
      s2[t] += s2[t + off];
    }
    __syncthreads();
  }
  if (t == 0) {
    segpart[(b * C_ + c) * NCHUNK + k] = s1[0];
    attpart[(b * C_ + c) * NCHUNK + k] = s2[0];
  }
}

// ---------------- kernel F: final 80 outputs ----------------
__global__ __launch_bounds__(128) void kF(const float* __restrict__ segpart,
                                          const float* __restrict__ attpart,
                                          const float* __restrict__ ws_scal,
                                          const float* __restrict__ bcls,
                                          float* __restrict__ out) {
  const int t = threadIdx.x;
  if (t < B_ * C_) {
    float s = 0.f, a = 0.f;
    for (int k = 0; k < NCHUNK; ++k) {
      s += segpart[t * NCHUNK + k];
      a += attpart[t * NCHUNK + k];
    }
    out[t] = s + ws_scal[1] * a + bcls[0];
  }
}

extern "C" void kernel_launch(void* const* d_in, const int* in_sizes, int n_in,
                              void* d_out, int out_size, void* d_ws, size_t ws_size,
                              hipStream_t stream) {
  const float* inp   = (const float*)d_in[0];
  const int*   attn  = (const int*)d_in[1];
  const int*   mlm   = (const int*)d_in[2];
  const float* Wh    = (const float*)d_in[3];
  const float* bh    = (const float*)d_in[4];
  const float* query = (const float*)d_in[5];
  const float* Wcls  = (const float*)d_in[6];
  const float* bcls  = (const float*)d_in[7];
  float* out = (float*)d_out;

  char* ws = (char*)d_ws;
  float* ws_scal  = (float*)(ws + OFF_SCAL);
  int*   endv     = (int*)(ws + OFF_END);
  int*   cnt      = (int*)(ws + OFF_CNT);
  int*   starts   = (int*)(ws + OFF_STARTS);
  float* mZ       = (float*)(ws + OFF_MZ);
  int*   list     = (int*)(ws + OFF_LIST);
  float* probpart = (float*)(ws + OFF_PP);
  float* probs    = (float*)(ws + OFF_PROBS);
  float* segpart  = (float*)(ws + OFF_SEG);
  float* attpart  = (float*)(ws + OFF_ATT);

  hipLaunchKernelGGL(kA, dim3(B_ + 1), dim3(256), 0, stream,
                     attn, mlm, query, Wcls, ws_scal, endv, cnt, starts, list);
  hipLaunchKernelGGL(kC, dim3(B_ * TILES * ASPLIT), dim3(256), 0, stream,
                     inp, Wh, bh, query, cnt, list, probpart);
  hipLaunchKernelGGL(kD, dim3(B_), dim3(256), 0, stream,
                     attn, cnt, list, probpart, ws_scal, probs, mZ);
  hipLaunchKernelGGL(kE, dim3(B_ * C_ * NCHUNK), dim3(256), 0, stream,
                     inp, attn, probs, starts, endv, mZ, Wcls, segpart, attpart);
  hipLaunchKernelGGL(kF, dim3(1), dim3(128), 0, stream,
                     segpart, attpart, ws_scal, bcls, out);
}

// Round 2
// 114.515 us; speedup vs baseline: 24.1201x; 24.1201x over previous
//
#include <hip/hip_runtime.h>
#include <hip/hip_bf16.h>
#include <math.h>

#define B_ 16
#define L_ 2048
#define H_ 1024
#define A_ 1024
#define C_ 5

#define NSPLIT 4           // A-dim split across blocks in MFMA kernel
#define MT 32              // rows per tile
#define NT 128             // a-cols per chunk
#define KT 64              // k-step
#define MAXTILES (B_ * L_ / MT)  // 1024 (covers any mask)
#define CS 64              // rows per chunk in segment-sum kernel
#define NCHUNK (L_ / CS)   // 32

typedef __attribute__((ext_vector_type(8))) short short8v;
typedef __attribute__((ext_vector_type(4))) float float4v;

// ---- workspace layout (bytes) ----
static constexpr size_t OFF_SCAL   = 0;        // 2 f: denom, wsum
static constexpr size_t OFF_END    = 64;       // B ints
static constexpr size_t OFF_CNT    = 192;      // B ints
static constexpr size_t OFF_STARTS = 320;      // B*C ints
static constexpr size_t OFF_MZ     = 1024;     // 2*B floats
static constexpr size_t OFF_NTOT   = 2048;     // 1 int
static constexpr size_t OFF_LIST   = 4096;                      // B*L ints
static constexpr size_t OFF_GLIST  = OFF_LIST + (size_t)B_ * L_ * 4;   // B*L ints
static constexpr size_t OFF_W16    = OFF_GLIST + (size_t)B_ * L_ * 4;  // A*H bf16
static constexpr size_t OFF_PP     = OFF_W16 + (size_t)A_ * H_ * 2;    // NSPLIT*B*L f
static constexpr size_t OFF_PROBS  = OFF_PP + (size_t)NSPLIT * B_ * L_ * 4;
static constexpr size_t OFF_SEG    = OFF_PROBS + (size_t)B_ * L_ * 4;
static constexpr size_t OFF_ATT    = OFF_SEG + (size_t)B_ * C_ * NCHUNK * 4;

static __device__ __forceinline__ unsigned short f2bf(float f) {
  unsigned u = __float_as_uint(f);
  unsigned r = (u >> 16) & 1u;
  return (unsigned short)((u + 0x7fffu + r) >> 16);
}

// ---------------- kernel A: masks -> {end, cnt, list, starts}; scalars ----------------
__global__ __launch_bounds__(256) void kA(const int* __restrict__ attn,
                                          const int* __restrict__ mlm,
                                          const float* __restrict__ query,
                                          const float* __restrict__ Wcls,
                                          float* __restrict__ ws_scal,
                                          int* __restrict__ endv,
                                          int* __restrict__ cnt,
                                          int* __restrict__ starts,
                                          int* __restrict__ list) {
  __shared__ int   scn[256];
  __shared__ float sfA[256];
  __shared__ float sfB[256];
  const int b = blockIdx.x;
  const int t = threadIdx.x;

  if (b < B_) {
    const int* arow = attn + (size_t)b * L_;
    const int* mrow = mlm + (size_t)b * L_;
    const int base = t * 8;

    int loc[8];
    int lc = 0;
    for (int j = 0; j < 8; ++j) {
      int l = base + j;
      if (arow[l] == 0) loc[lc++] = l;
    }
    scn[t] = lc;
    __syncthreads();
    for (int off = 1; off < 256; off <<= 1) {
      int v = (t >= off) ? scn[t - off] : 0;
      __syncthreads();
      scn[t] += v;
      __syncthreads();
    }
    int excl = scn[t] - lc;
    int total = scn[255];
    int* lrow = list + (size_t)b * L_;
    for (int j = 0; j < lc; ++j) lrow[excl + j] = loc[j];
    if (t == 0) {
      cnt[b] = total;
      endv[b] = L_ - total;
    }
    __syncthreads();

    int mloc[8];
    int mc = 0;
    for (int j = 0; j < 8; ++j) {
      int l = base + j;
      if (mrow[l] > 0) mloc[mc++] = l;
    }
    scn[t] = mc;
    __syncthreads();
    for (int off = 1; off < 256; off <<= 1) {
      int v = (t >= off) ? scn[t - off] : 0;
      __syncthreads();
      scn[t] += v;
      __syncthreads();
    }
    int mexcl = scn[t] - mc;
    for (int j = 0; j < mc; ++j) {
      int idx = mexcl + j;
      if (idx < C_) starts[b * C_ + idx] = mloc[j];
    }
  } else {
    float s = 0.f, s2 = 0.f;
    for (int i = t; i < A_; i += 256) {
      float q = query[i];
      s += q;
      s2 = fmaf(q, q, s2);
    }
    sfA[t] = s;
    sfB[t] = s2;
    __syncthreads();
    for (int off = 128; off >= 1; off >>= 1) {
      if (t < off) {
        sfA[t] += sfA[t + off];
        sfB[t] += sfB[t + off];
      }
      __syncthreads();
    }
    float qsum = sfA[0], qsq = sfB[0];
    __syncthreads();
    float w = 0.f;
    for (int i = t; i < H_; i += 256) w += Wcls[i];
    sfA[t] = w;
    __syncthreads();
    for (int off = 128; off >= 1; off >>= 1) {
      if (t < off) sfA[t] += sfA[t + off];
      __syncthreads();
    }
    if (t == 0) {
      float var = (qsq - qsum * qsum / (float)A_) / (float)(A_ - 1);
      ws_scal[0] = sqrtf((float)A_ * var);
      ws_scal[1] = sfA[0];
    }
  }
}

// ---------------- kernel W: W_hidden f32 -> bf16 ----------------
__global__ __launch_bounds__(256) void kW(const float* __restrict__ W,
                                          unsigned short* __restrict__ W16) {
  const size_t i = ((size_t)blockIdx.x * 256 + threadIdx.x) * 8;
  float4 u0 = *(const float4*)(W + i);
  float4 u1 = *(const float4*)(W + i + 4);
  union { short8v v; unsigned short h[8]; } o;
  o.h[0] = f2bf(u0.x); o.h[1] = f2bf(u0.y); o.h[2] = f2bf(u0.z); o.h[3] = f2bf(u0.w);
  o.h[4] = f2bf(u1.x); o.h[5] = f2bf(u1.y); o.h[6] = f2bf(u1.z); o.h[7] = f2bf(u1.w);
  *(short8v*)(W16 + i) = o.v;
}

// ---------------- kernel B: batch offsets + global row list ----------------
__global__ __launch_bounds__(256) void kB(const int* __restrict__ cnt,
                                          const int* __restrict__ list,
                                          int* __restrict__ glist,
                                          int* __restrict__ ntot) {
  __shared__ int offs[B_ + 1];
  const int t = threadIdx.x;
  if (t == 0) {
    int s = 0;
    for (int b = 0; b < B_; ++b) { offs[b] = s; s += cnt[b]; }
    offs[B_] = s;
    ntot[0] = s;
  }
  __syncthreads();
  for (int b = 0; b < B_; ++b) {
    const int c0 = cnt[b];
    const int o = offs[b];
    for (int i = t; i < c0; i += 256)
      glist[o + i] = (b << 16) | list[(size_t)b * L_ + i];
  }
}

// ---------------- kernel C: MFMA bf16 GEMM + tanh·query reduce ----------------
// block: 256 thr = 4 waves; tile = 32 masked rows; as-slice = 256 a-cols (2 chunks of 128)
__global__ __launch_bounds__(256) void kCm(const float* __restrict__ inp,
                                           const unsigned short* __restrict__ W16,
                                           const float* __restrict__ bh,
                                           const float* __restrict__ query,
                                           const int* __restrict__ glist,
                                           const int* __restrict__ ntot,
                                           float* __restrict__ probpart) {
  const int Ntot = ntot[0];
  const int bid = blockIdx.x;
  const int as = bid & (NSPLIT - 1);
  const int tile = bid >> 2;
  if (tile * MT >= Ntot) return;

  __shared__ __align__(16) unsigned short Xs[MT][72];   // +16B row pad
  __shared__ __align__(16) unsigned short Ws[NT][72];
  __shared__ float red[4][MT];

  const int t = threadIdx.x;
  const int w = t >> 6;
  const int lane = t & 63;
  const int lg = lane >> 4;
  const int lc = lane & 15;

  // staging decomposition: row = t>>3, 16B-seg = t&7
  const int srow = t >> 3;
  const int sseg = t & 7;
  const int gi = tile * MT + srow;
  size_t xaddr = 0;
  if (gi < Ntot) {
    int e = glist[gi];
    xaddr = ((size_t)((e >> 16) * L_ + (e & 0xffff))) * H_;
  }

  float pp[2][4];
#pragma unroll
  for (int m = 0; m < 2; ++m)
#pragma unroll
    for (int r = 0; r < 4; ++r) pp[m][r] = 0.f;

  for (int cc = 0; cc < 2; ++cc) {
    const int a0 = as * 256 + cc * NT;
    float4v acc[2][2];
#pragma unroll
    for (int m = 0; m < 2; ++m)
#pragma unroll
      for (int n = 0; n < 2; ++n) acc[m][n] = (float4v){0.f, 0.f, 0.f, 0.f};

    for (int h0 = 0; h0 < H_; h0 += KT) {
      __syncthreads();
      // stage X: 32 rows x 64 h (f32 -> bf16)
      {
        float4 u0 = *(const float4*)(inp + xaddr + h0 + sseg * 8);
        float4 u1 = *(const float4*)(inp + xaddr + h0 + sseg * 8 + 4);
        unsigned short* dst = &Xs[srow][sseg * 8];
        dst[0] = f2bf(u0.x); dst[1] = f2bf(u0.y); dst[2] = f2bf(u0.z); dst[3] = f2bf(u0.w);
        dst[4] = f2bf(u1.x); dst[5] = f2bf(u1.y); dst[6] = f2bf(u1.z); dst[7] = f2bf(u1.w);
      }
      // stage W: 128 rows x 64 h (bf16 16B chunks)
#pragma unroll
      for (int j = 0; j < 4; ++j) {
        const int r = srow + 32 * j;
        short8v wv = *(const short8v*)(W16 + (size_t)(a0 + r) * H_ + h0 + sseg * 8);
        *(short8v*)&Ws[r][sseg * 8] = wv;
      }
      __syncthreads();
#pragma unroll
      for (int kk = 0; kk < 2; ++kk) {
        const int off = kk * 32 + lg * 8;
        short8v av0 = *(const short8v*)&Xs[lc][off];
        short8v av1 = *(const short8v*)&Xs[16 + lc][off];
        short8v bv0 = *(const short8v*)&Ws[w * 32 + lc][off];
        short8v bv1 = *(const short8v*)&Ws[w * 32 + 16 + lc][off];
        acc[0][0] = __builtin_amdgcn_mfma_f32_16x16x32_bf16(av0, bv0, acc[0][0], 0, 0, 0);
        acc[0][1] = __builtin_amdgcn_mfma_f32_16x16x32_bf16(av0, bv1, acc[0][1], 0, 0, 0);
        acc[1][0] = __builtin_amdgcn_mfma_f32_16x16x32_bf16(av1, bv0, acc[1][0], 0, 0, 0);
        acc[1][1] = __builtin_amdgcn_mfma_f32_16x16x32_bf16(av1, bv1, acc[1][1], 0, 0, 0);
      }
    }
    // epilogue: bias + tanh + *query, accumulate per-row partials
#pragma unroll
    for (int n = 0; n < 2; ++n) {
      const int ag = a0 + w * 32 + n * 16 + lc;
      const float q = query[ag];
      const float bb = bh[ag];
#pragma unroll
      for (int m = 0; m < 2; ++m)
#pragma unroll
        for (int r = 0; r < 4; ++r) {
          float v = acc[m][n][r] + bb;
          pp[m][r] = fmaf(tanhf(v), q, pp[m][r]);
        }
    }
  }

  // reduce over the 16 col-lanes
#pragma unroll
  for (int m = 0; m < 2; ++m)
#pragma unroll
    for (int r = 0; r < 4; ++r) {
#pragma unroll
      for (int o = 1; o < 16; o <<= 1)
        pp[m][r] += __shfl_xor(pp[m][r], o, 64);
    }
  __syncthreads();
  if (lc == 0) {
#pragma unroll
    for (int m = 0; m < 2; ++m)
#pragma unroll
      for (int r = 0; r < 4; ++r)
        red[w][m * 16 + lg * 4 + r] = pp[m][r];
  }
  __syncthreads();
  if (t < MT) {
    const int i = tile * MT + t;
    if (i < Ntot) {
      float s = red[0][t] + red[1][t] + red[2][t] + red[3][t];
      int e = glist[i];
      probpart[((size_t)as * B_ + (e >> 16)) * L_ + (e & 0xffff)] = s;
    }
  }
}

// ---------------- kernel D: finalize probs, per-batch softmax scalars ----------------
__global__ __launch_bounds__(256) void kD(const int* __restrict__ attn,
                                          const int* __restrict__ cnt,
                                          const int* __restrict__ list,
                                          const float* __restrict__ probpart,
                                          const float* __restrict__ ws_scal,
                                          float* __restrict__ probs,
                                          float* __restrict__ mZ) {
  __shared__ float sred[256];
  const int b = blockIdx.x;
  const int t = threadIdx.x;
  const float denom = ws_scal[0];
  const int c0 = cnt[b];

  for (int i = t; i < c0; i += 256) {
    int l = list[(size_t)b * L_ + i];
    float s = 0.f;
    for (int as = 0; as < NSPLIT; ++as) s += probpart[((size_t)as * B_ + b) * L_ + l];
    probs[(size_t)b * L_ + l] = s / denom;
  }
  __syncthreads();

  const int* arow = attn + (size_t)b * L_;
  float mx = -1e30f;
  for (int l = t; l < L_; l += 256) {
    float lg = 0.f;
    if (arow[l] == 0) lg = -1000.0f * probs[(size_t)b * L_ + l];
    mx = fmaxf(mx, lg);
  }
  sred[t] = mx;
  __syncthreads();
  for (int off = 128; off >= 1; off >>= 1) {
    if (t < off) sred[t] = fmaxf(sred[t], sred[t + off]);
    __syncthreads();
  }
  const float m = sred[0];
  __syncthreads();

  float zs = 0.f;
  for (int l = t; l < L_; l += 256) {
    float lg = 0.f;
    if (arow[l] == 0) lg = -1000.0f * probs[(size_t)b * L_ + l];
    zs += expf(lg - m);
  }
  sred[t] = zs;
  __syncthreads();
  for (int off = 128; off >= 1; off >>= 1) {
    if (t < off) sred[t] += sred[t + off];
    __syncthreads();
  }
  if (t == 0) {
    mZ[b] = m;
    mZ[B_ + b] = sred[0];
  }
}

// ---------------- kernel E: segment chunk sums ----------------
__global__ __launch_bounds__(256) void kE(const float* __restrict__ inp,
                                          const int* __restrict__ attn,
                                          const float* __restrict__ probs,
                                          const int* __restrict__ starts,
                                          const int* __restrict__ endv,
                                          const float* __restrict__ mZ,
                                          const float* __restrict__ Wcls,
                                          float* __restrict__ segpart,
                                          float* __restrict__ attpart) {
  __shared__ float s1[256];
  __shared__ float s2[256];
  const int bid = blockIdx.x;
  const int k = bid % NCHUNK;
  const int c = (bid / NCHUNK) % C_;
  const int b = bid / (NCHUNK * C_);
  const int t = threadIdx.x;

  const int st = starts[b * C_ + c];
  const int bound = (c < C_ - 1) ? (starts[b * C_ + c + 1] - 1) : (endv[b] - 1);
  int lo = st + 1 + k * CS;
  int hi = st + 1 + (k + 1) * CS;
  if (bound < hi) hi = bound;

  const float m = mZ[b];
  const float Z = mZ[B_ + b];

  float4 vacc = make_float4(0.f, 0.f, 0.f, 0.f);
  float attacc = 0.f;
  if (lo < hi) {
    for (int l = lo; l < hi; ++l) {
      const float4* row = (const float4*)(inp + ((size_t)(b * L_ + l)) * H_);
      float4 v = row[t];
      vacc.x += v.x; vacc.y += v.y; vacc.z += v.z; vacc.w += v.w;
    }
    for (int l = lo + t; l < hi; l += 256) {
      float lg = 0.f;
      if (attn[(size_t)b * L_ + l] == 0) lg = -1000.0f * probs[(size_t)b * L_ + l];
      attacc += expf(lg - m) / Z;
    }
  }
  float pd = vacc.x * Wcls[4 * t] + vacc.y * Wcls[4 * t + 1] +
             vacc.z * Wcls[4 * t + 2] + vacc.w * Wcls[4 * t + 3];
  s1[t] = pd;
  s2[t] = attacc;
  __syncthreads();
  for (int off = 128; off >= 1; off >>= 1) {
    if (t < off) {
      s1[t] += s1[t + off];
      s2[t] += s2[t + off];
    }
    __syncthreads();
  }
  if (t == 0) {
    segpart[(b * C_ + c) * NCHUNK + k] = s1[0];
    attpart[(b * C_ + c) * NCHUNK + k] = s2[0];
  }
}

// ---------------- kernel F: final 80 outputs ----------------
__global__ __launch_bounds__(128) void kF(const float* __restrict__ segpart,
                                          const float* __restrict__ attpart,
                                          const float* __restrict__ ws_scal,
                                          const float* __restrict__ bcls,
                                          float* __restrict__ out) {
  const int t = threadIdx.x;
  if (t < B_ * C_) {
    float s = 0.f, a = 0.f;
    for (int k = 0; k < NCHUNK; ++k) {
      s += segpart[t * NCHUNK + k];
      a += attpart[t * NCHUNK + k];
    }
    out[t] = s + ws_scal[1] * a + bcls[0];
  }
}

extern "C" void kernel_launch(void* const* d_in, const int* in_sizes, int n_in,
                              void* d_out, int out_size, void* d_ws, size_t ws_size,
                              hipStream_t stream) {
  const float* inp   = (const float*)d_in[0];
  const int*   attn  = (const int*)d_in[1];
  const int*   mlm   = (const int*)d_in[2];
  const float* Wh    = (const float*)d_in[3];
  const float* bh    = (const float*)d_in[4];
  const float* query = (const float*)d_in[5];
  const float* Wcls  = (const float*)d_in[6];
  const float* bcls  = (const float*)d_in[7];
  float* out = (float*)d_out;

  char* ws = (char*)d_ws;
  float*          ws_scal = (float*)(ws + OFF_SCAL);
  int*            endv    = (int*)(ws + OFF_END);
  int*            cnt     = (int*)(ws + OFF_CNT);
  int*            starts  = (int*)(ws + OFF_STARTS);
  float*          mZ      = (float*)(ws + OFF_MZ);
  int*            ntotp   = (int*)(ws + OFF_NTOT);
  int*            list    = (int*)(ws + OFF_LIST);
  int*            glist   = (int*)(ws + OFF_GLIST);
  unsigned short* W16     = (unsigned short*)(ws + OFF_W16);
  float*          probpart= (float*)(ws + OFF_PP);
  float*          probs   = (float*)(ws + OFF_PROBS);
  float*          segpart = (float*)(ws + OFF_SEG);
  float*          attpart = (float*)(ws + OFF_ATT);

  hipLaunchKernelGGL(kW, dim3(A_ * H_ / (256 * 8)), dim3(256), 0, stream, Wh, W16);
  hipLaunchKernelGGL(kA, dim3(B_ + 1), dim3(256), 0, stream,
                     attn, mlm, query, Wcls, ws_scal, endv, cnt, starts, list);
  hipLaunchKernelGGL(kB, dim3(1), dim3(256), 0, stream, cnt, list, glist, ntotp);
  hipLaunchKernelGGL(kCm, dim3(MAXTILES * NSPLIT), dim3(256), 0, stream,
                     inp, W16, bh, query, glist, ntotp, probpart);
  hipLaunchKernelGGL(kD, dim3(B_), dim3(256), 0, stream,
                     attn, cnt, list, probpart, ws_scal, probs, mZ);
  hipLaunchKernelGGL(kE, dim3(B_ * C_ * NCHUNK), dim3(256), 0, stream,
                     inp, attn, probs, starts, endv, mZ, Wcls, segpart, attpart);
  hipLaunchKernelGGL(kF, dim3(1), dim3(128), 0, stream,
                     segpart, attpart, ws_scal, bcls, out);
}

// Round 3
// 89.047 us; speedup vs baseline: 31.0185x; 1.2860x over previous
//
#include <hip/hip_runtime.h>
#include <hip/hip_bf16.h>
#include <math.h>

#define B_ 16
#define L_ 2048
#define H_ 1024
#define A_ 1024
#define C_ 5

#define NSPLIT 4           // A-dim split across blocks in MFMA kernel
#define MT 32              // rows per tile
#define NT 128             // a-cols per chunk
#define KT 64              // k-step
#define MAXTILES (B_ * L_ / MT)  // 1024 (covers any mask)

typedef __attribute__((ext_vector_type(8))) short short8v;
typedef __attribute__((ext_vector_type(4))) float float4v;

// ---- workspace layout (bytes) ----
static constexpr size_t OFF_SCAL   = 0;        // 2 f: denom, wsum
static constexpr size_t OFF_END    = 64;       // B ints
static constexpr size_t OFF_CNT    = 192;      // B ints
static constexpr size_t OFF_STARTS = 320;      // B*C ints
static constexpr size_t OFF_MZ     = 1024;     // 2*B floats
static constexpr size_t OFF_NTOT   = 2048;     // 1 int
static constexpr size_t OFF_LIST   = 4096;                      // B*L ints
static constexpr size_t OFF_GLIST  = OFF_LIST + (size_t)B_ * L_ * 4;   // B*L ints
static constexpr size_t OFF_W16    = OFF_GLIST + (size_t)B_ * L_ * 4;  // A*H bf16
static constexpr size_t OFF_PP     = OFF_W16 + (size_t)A_ * H_ * 2;    // NSPLIT*B*L f
static constexpr size_t OFF_PROBS  = OFF_PP + (size_t)NSPLIT * B_ * L_ * 4;
static constexpr size_t OFF_D      = OFF_PROBS + (size_t)B_ * L_ * 4;  // B*L floats

static __device__ __forceinline__ unsigned short f2bf(float f) {
  unsigned u = __float_as_uint(f);
  unsigned r = (u >> 16) & 1u;
  return (unsigned short)((u + 0x7fffu + r) >> 16);
}

// ---------------- kernel A: masks -> {end, cnt, list, starts}; scalars ----------------
__global__ __launch_bounds__(256) void kA(const int* __restrict__ attn,
                                          const int* __restrict__ mlm,
                                          const float* __restrict__ query,
                                          const float* __restrict__ Wcls,
                                          float* __restrict__ ws_scal,
                                          int* __restrict__ endv,
                                          int* __restrict__ cnt,
                                          int* __restrict__ starts,
                                          int* __restrict__ list) {
  __shared__ int   scn[256];
  __shared__ float sfA[256];
  __shared__ float sfB[256];
  const int b = blockIdx.x;
  const int t = threadIdx.x;

  if (b < B_) {
    const int* arow = attn + (size_t)b * L_;
    const int* mrow = mlm + (size_t)b * L_;
    const int base = t * 8;

    int loc[8];
    int lc = 0;
    for (int j = 0; j < 8; ++j) {
      int l = base + j;
      if (arow[l] == 0) loc[lc++] = l;
    }
    scn[t] = lc;
    __syncthreads();
    for (int off = 1; off < 256; off <<= 1) {
      int v = (t >= off) ? scn[t - off] : 0;
      __syncthreads();
      scn[t] += v;
      __syncthreads();
    }
    int excl = scn[t] - lc;
    int total = scn[255];
    int* lrow = list + (size_t)b * L_;
    for (int j = 0; j < lc; ++j) lrow[excl + j] = loc[j];
    if (t == 0) {
      cnt[b] = total;
      endv[b] = L_ - total;
    }
    __syncthreads();

    int mloc[8];
    int mc = 0;
    for (int j = 0; j < 8; ++j) {
      int l = base + j;
      if (mrow[l] > 0) mloc[mc++] = l;
    }
    scn[t] = mc;
    __syncthreads();
    for (int off = 1; off < 256; off <<= 1) {
      int v = (t >= off) ? scn[t - off] : 0;
      __syncthreads();
      scn[t] += v;
      __syncthreads();
    }
    int mexcl = scn[t] - mc;
    for (int j = 0; j < mc; ++j) {
      int idx = mexcl + j;
      if (idx < C_) starts[b * C_ + idx] = mloc[j];
    }
  } else {
    float s = 0.f, s2 = 0.f;
    for (int i = t; i < A_; i += 256) {
      float q = query[i];
      s += q;
      s2 = fmaf(q, q, s2);
    }
    sfA[t] = s;
    sfB[t] = s2;
    __syncthreads();
    for (int off = 128; off >= 1; off >>= 1) {
      if (t < off) {
        sfA[t] += sfA[t + off];
        sfB[t] += sfB[t + off];
      }
      __syncthreads();
    }
    float qsum = sfA[0], qsq = sfB[0];
    __syncthreads();
    float w = 0.f;
    for (int i = t; i < H_; i += 256) w += Wcls[i];
    sfA[t] = w;
    __syncthreads();
    for (int off = 128; off >= 1; off >>= 1) {
      if (t < off) sfA[t] += sfA[t + off];
      __syncthreads();
    }
    if (t == 0) {
      float var = (qsq - qsum * qsum / (float)A_) / (float)(A_ - 1);
      ws_scal[0] = sqrtf((float)A_ * var);
      ws_scal[1] = sfA[0];
    }
  }
}

// ---------------- kernel W: W_hidden f32 -> bf16 ----------------
__global__ __launch_bounds__(256) void kW(const float* __restrict__ W,
                                          unsigned short* __restrict__ W16) {
  const size_t i = ((size_t)blockIdx.x * 256 + threadIdx.x) * 8;
  float4 u0 = *(const float4*)(W + i);
  float4 u1 = *(const float4*)(W + i + 4);
  union { short8v v; unsigned short h[8]; } o;
  o.h[0] = f2bf(u0.x); o.h[1] = f2bf(u0.y); o.h[2] = f2bf(u0.z); o.h[3] = f2bf(u0.w);
  o.h[4] = f2bf(u1.x); o.h[5] = f2bf(u1.y); o.h[6] = f2bf(u1.z); o.h[7] = f2bf(u1.w);
  *(short8v*)(W16 + i) = o.v;
}

// ---------------- kernel B: batch offsets + global row list ----------------
__global__ __launch_bounds__(256) void kB(const int* __restrict__ cnt,
                                          const int* __restrict__ list,
                                          int* __restrict__ glist,
                                          int* __restrict__ ntot) {
  __shared__ int offs[B_ + 1];
  const int t = threadIdx.x;
  if (t == 0) {
    int s = 0;
    for (int b = 0; b < B_; ++b) { offs[b] = s; s += cnt[b]; }
    offs[B_] = s;
    ntot[0] = s;
  }
  __syncthreads();
  for (int b = 0; b < B_; ++b) {
    const int c0 = cnt[b];
    const int o = offs[b];
    for (int i = t; i < c0; i += 256)
      glist[o + i] = (b << 16) | list[(size_t)b * L_ + i];
  }
}

// ---------------- kernel C: MFMA bf16 GEMM + tanh·query reduce ----------------
__global__ __launch_bounds__(256) void kCm(const float* __restrict__ inp,
                                           const unsigned short* __restrict__ W16,
                                           const float* __restrict__ bh,
                                           const float* __restrict__ query,
                                           const int* __restrict__ glist,
                                           const int* __restrict__ ntot,
                                           float* __restrict__ probpart) {
  const int Ntot = ntot[0];
  const int bid = blockIdx.x;
  const int as = bid & (NSPLIT - 1);
  const int tile = bid >> 2;
  if (tile * MT >= Ntot) return;

  __shared__ __align__(16) unsigned short Xs[MT][72];   // +16B row pad
  __shared__ __align__(16) unsigned short Ws[NT][72];
  __shared__ float red[4][MT];

  const int t = threadIdx.x;
  const int w = t >> 6;
  const int lane = t & 63;
  const int lg = lane >> 4;
  const int lc = lane & 15;

  const int srow = t >> 3;
  const int sseg = t & 7;
  const int gi = tile * MT + srow;
  size_t xaddr = 0;
  if (gi < Ntot) {
    int e = glist[gi];
    xaddr = ((size_t)((e >> 16) * L_ + (e & 0xffff))) * H_;
  }

  float pp[2][4];
#pragma unroll
  for (int m = 0; m < 2; ++m)
#pragma unroll
    for (int r = 0; r < 4; ++r) pp[m][r] = 0.f;

  for (int cc = 0; cc < 2; ++cc) {
    const int a0 = as * 256 + cc * NT;
    float4v acc[2][2];
#pragma unroll
    for (int m = 0; m < 2; ++m)
#pragma unroll
      for (int n = 0; n < 2; ++n) acc[m][n] = (float4v){0.f, 0.f, 0.f, 0.f};

    for (int h0 = 0; h0 < H_; h0 += KT) {
      __syncthreads();
      {
        float4 u0 = *(const float4*)(inp + xaddr + h0 + sseg * 8);
        float4 u1 = *(const float4*)(inp + xaddr + h0 + sseg * 8 + 4);
        unsigned short* dst = &Xs[srow][sseg * 8];
        dst[0] = f2bf(u0.x); dst[1] = f2bf(u0.y); dst[2] = f2bf(u0.z); dst[3] = f2bf(u0.w);
        dst[4] = f2bf(u1.x); dst[5] = f2bf(u1.y); dst[6] = f2bf(u1.z); dst[7] = f2bf(u1.w);
      }
#pragma unroll
      for (int j = 0; j < 4; ++j) {
        const int r = srow + 32 * j;
        short8v wv = *(const short8v*)(W16 + (size_t)(a0 + r) * H_ + h0 + sseg * 8);
        *(short8v*)&Ws[r][sseg * 8] = wv;
      }
      __syncthreads();
#pragma unroll
      for (int kk = 0; kk < 2; ++kk) {
        const int off = kk * 32 + lg * 8;
        short8v av0 = *(const short8v*)&Xs[lc][off];
        short8v av1 = *(const short8v*)&Xs[16 + lc][off];
        short8v bv0 = *(const short8v*)&Ws[w * 32 + lc][off];
        short8v bv1 = *(const short8v*)&Ws[w * 32 + 16 + lc][off];
        acc[0][0] = __builtin_amdgcn_mfma_f32_16x16x32_bf16(av0, bv0, acc[0][0], 0, 0, 0);
        acc[0][1] = __builtin_amdgcn_mfma_f32_16x16x32_bf16(av0, bv1, acc[0][1], 0, 0, 0);
        acc[1][0] = __builtin_amdgcn_mfma_f32_16x16x32_bf16(av1, bv0, acc[1][0], 0, 0, 0);
        acc[1][1] = __builtin_amdgcn_mfma_f32_16x16x32_bf16(av1, bv1, acc[1][1], 0, 0, 0);
      }
    }
#pragma unroll
    for (int n = 0; n < 2; ++n) {
      const int ag = a0 + w * 32 + n * 16 + lc;
      const float q = query[ag];
      const float bb = bh[ag];
#pragma unroll
      for (int m = 0; m < 2; ++m)
#pragma unroll
        for (int r = 0; r < 4; ++r) {
          float v = acc[m][n][r] + bb;
          pp[m][r] = fmaf(tanhf(v), q, pp[m][r]);
        }
    }
  }

#pragma unroll
  for (int m = 0; m < 2; ++m)
#pragma unroll
    for (int r = 0; r < 4; ++r) {
#pragma unroll
      for (int o = 1; o < 16; o <<= 1)
        pp[m][r] += __shfl_xor(pp[m][r], o, 64);
    }
  __syncthreads();
  if (lc == 0) {
#pragma unroll
    for (int m = 0; m < 2; ++m)
#pragma unroll
      for (int r = 0; r < 4; ++r)
        red[w][m * 16 + lg * 4 + r] = pp[m][r];
  }
  __syncthreads();
  if (t < MT) {
    const int i = tile * MT + t;
    if (i < Ntot) {
      float s = red[0][t] + red[1][t] + red[2][t] + red[3][t];
      int e = glist[i];
      probpart[((size_t)as * B_ + (e >> 16)) * L_ + (e & 0xffff)] = s;
    }
  }
}

// ---------------- kernel D: finalize probs, per-batch softmax scalars ----------------
__global__ __launch_bounds__(256) void kD(const int* __restrict__ attn,
                                          const int* __restrict__ cnt,
                                          const int* __restrict__ list,
                                          const float* __restrict__ probpart,
                                          const float* __restrict__ ws_scal,
                                          float* __restrict__ probs,
                                          float* __restrict__ mZ) {
  __shared__ float sred[256];
  const int b = blockIdx.x;
  const int t = threadIdx.x;
  const float denom = ws_scal[0];
  const int c0 = cnt[b];

  for (int i = t; i < c0; i += 256) {
    int l = list[(size_t)b * L_ + i];
    float s = 0.f;
    for (int as = 0; as < NSPLIT; ++as) s += probpart[((size_t)as * B_ + b) * L_ + l];
    probs[(size_t)b * L_ + l] = s / denom;
  }
  __syncthreads();

  const int* arow = attn + (size_t)b * L_;
  float mx = -1e30f;
  for (int l = t; l < L_; l += 256) {
    float lg = 0.f;
    if (arow[l] == 0) lg = -1000.0f * probs[(size_t)b * L_ + l];
    mx = fmaxf(mx, lg);
  }
  sred[t] = mx;
  __syncthreads();
  for (int off = 128; off >= 1; off >>= 1) {
    if (t < off) sred[t] = fmaxf(sred[t], sred[t + off]);
    __syncthreads();
  }
  const float m = sred[0];
  __syncthreads();

  float zs = 0.f;
  for (int l = t; l < L_; l += 256) {
    float lg = 0.f;
    if (arow[l] == 0) lg = -1000.0f * probs[(size_t)b * L_ + l];
    zs += expf(lg - m);
  }
  sred[t] = zs;
  __syncthreads();
  for (int off = 128; off >= 1; off >>= 1) {
    if (t < off) sred[t] += sred[t + off];
    __syncthreads();
  }
  if (t == 0) {
    mZ[b] = m;
    mZ[B_ + b] = sred[0];
  }
}

// ---------------- kernel E2: per-row dot with W_cls (full stream) ----------------
// one wave per row; skips rows >= end[b] (exactly the masked rows kCm reads)
__global__ __launch_bounds__(256) void kE2(const float* __restrict__ inp,
                                           const int* __restrict__ endv,
                                           const float* __restrict__ Wcls,
                                           float* __restrict__ d) {
  const int row = blockIdx.x * 4 + (threadIdx.x >> 6);
  const int lane = threadIdx.x & 63;
  const int b = row >> 11;
  const int l = row & (L_ - 1);
  if (l >= endv[b]) return;

  const float* r = inp + (size_t)row * H_;
  float acc = 0.f;
#pragma unroll
  for (int k = 0; k < 4; ++k) {
    float4 v = *(const float4*)(r + k * 256 + lane * 4);
    float4 wv = *(const float4*)(Wcls + k * 256 + lane * 4);
    acc += v.x * wv.x + v.y * wv.y + v.z * wv.z + v.w * wv.w;
  }
#pragma unroll
  for (int o = 1; o < 64; o <<= 1) acc += __shfl_xor(acc, o, 64);
  if (lane == 0) d[row] = acc;
}

// ---------------- kernel G: 80 outputs ----------------
// out[b,c] = sum_{l in seg} d[b,l] + wsum * nrows * exp(-m)/Z + bcls
__global__ __launch_bounds__(256) void kG(const float* __restrict__ d,
                                          const int* __restrict__ starts,
                                          const int* __restrict__ endv,
                                          const float* __restrict__ mZ,
                                          const float* __restrict__ ws_scal,
                                          const float* __restrict__ bcls,
                                          float* __restrict__ out) {
  __shared__ float s[256];
  const int bc = blockIdx.x;
  const int b = bc / C_;
  const int c = bc % C_;
  const int t = threadIdx.x;

  const int st = starts[b * C_ + c];
  const int bound = (c < C_ - 1) ? (starts[b * C_ + c + 1] - 1) : (endv[b] - 1);
  const int lo = st + 1;
  const int hi = bound;

  float acc = 0.f;
  for (int l = lo + t; l < hi; l += 256) acc += d[(size_t)b * L_ + l];
  s[t] = acc;
  __syncthreads();
  for (int off = 128; off >= 1; off >>= 1) {
    if (t < off) s[t] += s[t + off];
    __syncthreads();
  }
  if (t == 0) {
    int count = hi - lo;
    if (count < 0) count = 0;
    const float m = mZ[b];
    const float Z = mZ[B_ + b];
    const float att = expf(-m) / Z;   // att value at all attended positions
    out[bc] = s[0] + ws_scal[1] * att * (float)count + bcls[0];
  }
}

extern "C" void kernel_launch(void* const* d_in, const int* in_sizes, int n_in,
                              void* d_out, int out_size, void* d_ws, size_t ws_size,
                              hipStream_t stream) {
  const float* inp   = (const float*)d_in[0];
  const int*   attn  = (const int*)d_in[1];
  const int*   mlm   = (const int*)d_in[2];
  const float* Wh    = (const float*)d_in[3];
  const float* bh    = (const float*)d_in[4];
  const float* query = (const float*)d_in[5];
  const float* Wcls  = (const float*)d_in[6];
  const float* bcls  = (const float*)d_in[7];
  float* out = (float*)d_out;

  char* ws = (char*)d_ws;
  float*          ws_scal = (float*)(ws + OFF_SCAL);
  int*            endv    = (int*)(ws + OFF_END);
  int*            cnt     = (int*)(ws + OFF_CNT);
  int*            starts  = (int*)(ws + OFF_STARTS);
  float*          mZ      = (float*)(ws + OFF_MZ);
  int*            ntotp   = (int*)(ws + OFF_NTOT);
  int*            list    = (int*)(ws + OFF_LIST);
  int*            glist   = (int*)(ws + OFF_GLIST);
  unsigned short* W16     = (unsigned short*)(ws + OFF_W16);
  float*          probpart= (float*)(ws + OFF_PP);
  float*          probs   = (float*)(ws + OFF_PROBS);
  float*          dvec    = (float*)(ws + OFF_D);

  hipLaunchKernelGGL(kW, dim3(A_ * H_ / (256 * 8)), dim3(256), 0, stream, Wh, W16);
  hipLaunchKernelGGL(kA, dim3(B_ + 1), dim3(256), 0, stream,
                     attn, mlm, query, Wcls, ws_scal, endv, cnt, starts, list);
  hipLaunchKernelGGL(kB, dim3(1), dim3(256), 0, stream, cnt, list, glist, ntotp);
  hipLaunchKernelGGL(kE2, dim3(B_ * L_ / 4), dim3(256), 0, stream, inp, endv, Wcls, dvec);
  hipLaunchKernelGGL(kCm, dim3(MAXTILES * NSPLIT), dim3(256), 0, stream,
                     inp, W16, bh, query, glist, ntotp, probpart);
  hipLaunchKernelGGL(kD, dim3(B_), dim3(256), 0, stream,
                     attn, cnt, list, probpart, ws_scal, probs, mZ);
  hipLaunchKernelGGL(kG, dim3(B_ * C_), dim3(256), 0, stream,
                     dvec, starts, endv, mZ, ws_scal, bcls, out);
}

// Round 4
// 68.769 us; speedup vs baseline: 40.1651x; 1.2949x over previous
//
#include <hip/hip_runtime.h>
#include <hip/hip_bf16.h>
#include <math.h>

#define B_ 16
#define L_ 2048
#define H_ 1024
#define A_ 1024
#define C_ 5

#define NSPLIT 4                 // A-dim split across blocks in MFMA part
#define MT 32                    // rows per tile
#define NT 128                   // a-cols per chunk
#define KT 64                    // k-step
#define TPB 16                   // tiles per batch (covers 512 masked rows; generator max is 511)
#define KC_BLOCKS (B_ * TPB * NSPLIT)   // 1024 MFMA blocks
#define KE_BLOCKS (B_ * L_ / 4)         // 8192 streaming blocks (4 rows each)
#define KW_BLOCKS (A_ * H_ / (256 * 8)) // 512 W-convert blocks

typedef __attribute__((ext_vector_type(8))) short short8v;
typedef __attribute__((ext_vector_type(4))) float float4v;

// ---- workspace layout (bytes) ----
static constexpr size_t OFF_SCAL   = 0;        // 2 f: denom, wsum
static constexpr size_t OFF_END    = 64;       // B ints
static constexpr size_t OFF_CNT    = 192;      // B ints
static constexpr size_t OFF_STARTS = 320;      // B*C ints
static constexpr size_t OFF_LIST   = 4096;                              // B*L ints
static constexpr size_t OFF_W16    = OFF_LIST + (size_t)B_ * L_ * 4;    // A*H bf16
static constexpr size_t OFF_PP     = OFF_W16 + (size_t)A_ * H_ * 2;     // NSPLIT*B*L f
static constexpr size_t OFF_D      = OFF_PP + (size_t)NSPLIT * B_ * L_ * 4;  // B*L f

static __device__ __forceinline__ unsigned short f2bf(float f) {
  unsigned u = __float_as_uint(f);
  unsigned r = (u >> 16) & 1u;
  return (unsigned short)((u + 0x7fffu + r) >> 16);
}

// ============ kernel 1: kWA — masks + scalars + W f32->bf16 ============
// blocks [0,B): per-batch mask compaction (wave-scan based)
// block B: qvar/denom + wsum scalars
// blocks [B+1, B+1+KW_BLOCKS): W conversion
__global__ __launch_bounds__(256) void kWA(const int* __restrict__ attn,
                                           const int* __restrict__ mlm,
                                           const float* __restrict__ query,
                                           const float* __restrict__ Wcls,
                                           const float* __restrict__ Wh,
                                           float* __restrict__ ws_scal,
                                           int* __restrict__ endv,
                                           int* __restrict__ cnt,
                                           int* __restrict__ starts,
                                           int* __restrict__ list,
                                           unsigned short* __restrict__ W16) {
  __shared__ int   wsh[4];
  __shared__ float sf1[256];
  __shared__ float sf2[256];
  const int bid = blockIdx.x;
  const int t = threadIdx.x;

  if (bid < B_) {
    const int b = bid;
    const int* arow = attn + (size_t)b * L_;
    const int* mrow = mlm + (size_t)b * L_;
    const int w = t >> 6;
    const int lane = t & 63;
    const int base = t * 8;

    // ---- pass 1: attn==0 compaction (ascending) ----
    int loc[8];
    int lc = 0;
#pragma unroll
    for (int j = 0; j < 8; ++j) {
      int l = base + j;
      if (arow[l] == 0) loc[lc++] = l;
    }
    int incl = lc;
#pragma unroll
    for (int o = 1; o < 64; o <<= 1) {
      int v = __shfl_up(incl, o, 64);
      if (lane >= o) incl += v;
    }
    if (lane == 63) wsh[w] = incl;
    __syncthreads();
    int pre = 0, total = 0;
#pragma unroll
    for (int i = 0; i < 4; ++i) {
      int s = wsh[i];
      if (i < w) pre += s;
      total += s;
    }
    int excl = pre + incl - lc;
    int* lrow = list + (size_t)b * L_;
    for (int j = 0; j < lc; ++j) lrow[excl + j] = loc[j];
    if (t == 0) {
      cnt[b] = total;
      endv[b] = L_ - total;
    }
    __syncthreads();

    // ---- pass 2: mlm>0 markers ----
    int mloc[8];
    int mc = 0;
#pragma unroll
    for (int j = 0; j < 8; ++j) {
      int l = base + j;
      if (mrow[l] > 0) mloc[mc++] = l;
    }
    int incl2 = mc;
#pragma unroll
    for (int o = 1; o < 64; o <<= 1) {
      int v = __shfl_up(incl2, o, 64);
      if (lane >= o) incl2 += v;
    }
    if (lane == 63) wsh[w] = incl2;
    __syncthreads();
    int pre2 = 0;
#pragma unroll
    for (int i = 0; i < 4; ++i) {
      if (i < w) pre2 += wsh[i];
    }
    int excl2 = pre2 + incl2 - mc;
    for (int j = 0; j < mc; ++j) {
      int idx = excl2 + j;
      if (idx < C_) starts[b * C_ + idx] = mloc[j];
    }
  } else if (bid == B_) {
    // ---- scalars ----
    float s = 0.f, s2 = 0.f;
    for (int i = t; i < A_; i += 256) {
      float q = query[i];
      s += q;
      s2 = fmaf(q, q, s2);
    }
    sf1[t] = s;
    sf2[t] = s2;
    __syncthreads();
    for (int off = 128; off >= 1; off >>= 1) {
      if (t < off) {
        sf1[t] += sf1[t + off];
        sf2[t] += sf2[t + off];
      }
      __syncthreads();
    }
    float qsum = sf1[0], qsq = sf2[0];
    __syncthreads();
    float wv = 0.f;
    for (int i = t; i < H_; i += 256) wv += Wcls[i];
    sf1[t] = wv;
    __syncthreads();
    for (int off = 128; off >= 1; off >>= 1) {
      if (t < off) sf1[t] += sf1[t + off];
      __syncthreads();
    }
    if (t == 0) {
      float var = (qsq - qsum * qsum / (float)A_) / (float)(A_ - 1);
      ws_scal[0] = sqrtf((float)A_ * var);
      ws_scal[1] = sf1[0];
    }
  } else {
    // ---- W conversion ----
    const size_t i = ((size_t)(bid - B_ - 1) * 256 + t) * 8;
    float4 u0 = *(const float4*)(Wh + i);
    float4 u1 = *(const float4*)(Wh + i + 4);
    union { short8v v; unsigned short h[8]; } o;
    o.h[0] = f2bf(u0.x); o.h[1] = f2bf(u0.y); o.h[2] = f2bf(u0.z); o.h[3] = f2bf(u0.w);
    o.h[4] = f2bf(u1.x); o.h[5] = f2bf(u1.y); o.h[6] = f2bf(u1.z); o.h[7] = f2bf(u1.w);
    *(short8v*)(W16 + i) = o.v;
  }
}

// ============ kernel 2: kMain — MFMA probs GEMM + full-row W_cls dots ============
// bids [0, KC_BLOCKS): MFMA part, idx -> (b, tile, as)
// bids [KC_BLOCKS, +KE_BLOCKS): one wave per row, d[row] = dot(input row, Wcls)
__global__ __launch_bounds__(256) void kMain(const float* __restrict__ inp,
                                             const unsigned short* __restrict__ W16,
                                             const float* __restrict__ bh,
                                             const float* __restrict__ query,
                                             const float* __restrict__ Wcls,
                                             const int* __restrict__ attn,
                                             const int* __restrict__ cnt,
                                             const int* __restrict__ list,
                                             float* __restrict__ probpart,
                                             float* __restrict__ d) {
  __shared__ __align__(16) unsigned short Xs[MT][72];   // +16B row pad
  __shared__ __align__(16) unsigned short Ws[NT][72];
  __shared__ float red[4][MT];

  const int bid = blockIdx.x;
  const int t = threadIdx.x;

  if (bid >= KC_BLOCKS) {
    // ---- streaming part: one wave per row ----
    const int row = (bid - KC_BLOCKS) * 4 + (t >> 6);
    const int lane = t & 63;
    if (attn[row] == 0) return;   // masked rows handled by the MFMA part
    const float* r = inp + (size_t)row * H_;
    float acc = 0.f;
#pragma unroll
    for (int k = 0; k < 4; ++k) {
      float4 v = *(const float4*)(r + k * 256 + lane * 4);
      float4 wv = *(const float4*)(Wcls + k * 256 + lane * 4);
      acc += v.x * wv.x + v.y * wv.y + v.z * wv.z + v.w * wv.w;
    }
#pragma unroll
    for (int o = 1; o < 64; o <<= 1) acc += __shfl_xor(acc, o, 64);
    if (lane == 0) d[row] = acc;
    return;
  }

  // ---- MFMA part ----
  const int as = bid & (NSPLIT - 1);
  const int tile = (bid >> 2) & (TPB - 1);
  const int b = bid >> 6;   // NSPLIT*TPB = 64
  const int c0 = cnt[b];
  if (tile * MT >= c0) return;

  const int w = t >> 6;
  const int lane = t & 63;
  const int lg = lane >> 4;
  const int lc = lane & 15;

  const int srow = t >> 3;
  const int sseg = t & 7;
  const int gi = tile * MT + srow;
  size_t xaddr = 0;
  if (gi < c0) {
    int l = list[(size_t)b * L_ + gi];
    xaddr = ((size_t)(b * L_ + l)) * H_;
  }

  float pp[2][4];
#pragma unroll
  for (int m = 0; m < 2; ++m)
#pragma unroll
    for (int r = 0; r < 4; ++r) pp[m][r] = 0.f;

  for (int cc = 0; cc < 2; ++cc) {
    const int a0 = as * 256 + cc * NT;
    float4v acc[2][2];
#pragma unroll
    for (int m = 0; m < 2; ++m)
#pragma unroll
      for (int n = 0; n < 2; ++n) acc[m][n] = (float4v){0.f, 0.f, 0.f, 0.f};

    for (int h0 = 0; h0 < H_; h0 += KT) {
      __syncthreads();
      {
        float4 u0 = *(const float4*)(inp + xaddr + h0 + sseg * 8);
        float4 u1 = *(const float4*)(inp + xaddr + h0 + sseg * 8 + 4);
        unsigned short* dst = &Xs[srow][sseg * 8];
        dst[0] = f2bf(u0.x); dst[1] = f2bf(u0.y); dst[2] = f2bf(u0.z); dst[3] = f2bf(u0.w);
        dst[4] = f2bf(u1.x); dst[5] = f2bf(u1.y); dst[6] = f2bf(u1.z); dst[7] = f2bf(u1.w);
      }
#pragma unroll
      for (int j = 0; j < 4; ++j) {
        const int r = srow + 32 * j;
        short8v wv = *(const short8v*)(W16 + (size_t)(a0 + r) * H_ + h0 + sseg * 8);
        *(short8v*)&Ws[r][sseg * 8] = wv;
      }
      __syncthreads();
#pragma unroll
      for (int kk = 0; kk < 2; ++kk) {
        const int off = kk * 32 + lg * 8;
        short8v av0 = *(const short8v*)&Xs[lc][off];
        short8v av1 = *(const short8v*)&Xs[16 + lc][off];
        short8v bv0 = *(const short8v*)&Ws[w * 32 + lc][off];
        short8v bv1 = *(const short8v*)&Ws[w * 32 + 16 + lc][off];
        acc[0][0] = __builtin_amdgcn_mfma_f32_16x16x32_bf16(av0, bv0, acc[0][0], 0, 0, 0);
        acc[0][1] = __builtin_amdgcn_mfma_f32_16x16x32_bf16(av0, bv1, acc[0][1], 0, 0, 0);
        acc[1][0] = __builtin_amdgcn_mfma_f32_16x16x32_bf16(av1, bv0, acc[1][0], 0, 0, 0);
        acc[1][1] = __builtin_amdgcn_mfma_f32_16x16x32_bf16(av1, bv1, acc[1][1], 0, 0, 0);
      }
    }
#pragma unroll
    for (int n = 0; n < 2; ++n) {
      const int ag = a0 + w * 32 + n * 16 + lc;
      const float q = query[ag];
      const float bb = bh[ag];
#pragma unroll
      for (int m = 0; m < 2; ++m)
#pragma unroll
        for (int r = 0; r < 4; ++r) {
          float v = acc[m][n][r] + bb;
          pp[m][r] = fmaf(tanhf(v), q, pp[m][r]);
        }
    }
  }

#pragma unroll
  for (int m = 0; m < 2; ++m)
#pragma unroll
    for (int r = 0; r < 4; ++r) {
#pragma unroll
      for (int o = 1; o < 16; o <<= 1)
        pp[m][r] += __shfl_xor(pp[m][r], o, 64);
    }
  __syncthreads();
  if (lc == 0) {
#pragma unroll
    for (int m = 0; m < 2; ++m)
#pragma unroll
      for (int r = 0; r < 4; ++r)
        red[w][m * 16 + lg * 4 + r] = pp[m][r];
  }
  __syncthreads();
  if (t < MT) {
    const int i = tile * MT + t;
    if (i < c0) {
      float s = red[0][t] + red[1][t] + red[2][t] + red[3][t];
      int l = list[(size_t)b * L_ + i];
      probpart[((size_t)as * B_ + b) * L_ + l] = s;
    }
  }
}

// ============ kernel 3: kT — softmax scalars + segment sums + 80 outputs ============
// one block per batch; writes out[b*C .. b*C+C)
__global__ __launch_bounds__(256) void kT(const int* __restrict__ cnt,
                                          const int* __restrict__ list,
                                          const float* __restrict__ probpart,
                                          const float* __restrict__ ws_scal,
                                          const float* __restrict__ d,
                                          const int* __restrict__ starts,
                                          const int* __restrict__ endv,
                                          const float* __restrict__ bcls,
                                          float* __restrict__ out) {
  __shared__ float lg[L_];
  __shared__ float red[256];
  const int b = blockIdx.x;
  const int t = threadIdx.x;
  const float denom = ws_scal[0];
  const int c0 = cnt[b];

  // logits at masked positions; attended logits are exactly 0
  float mx = 0.0f;  // L > c0 always (valid length >= 64), so 0 participates in max
  for (int i = t; i < c0; i += 256) {
    int l = list[(size_t)b * L_ + i];
    float s = probpart[((size_t)0 * B_ + b) * L_ + l]
            + probpart[((size_t)1 * B_ + b) * L_ + l]
            + probpart[((size_t)2 * B_ + b) * L_ + l]
            + probpart[((size_t)3 * B_ + b) * L_ + l];
    float v = -1000.0f * (s / denom);
    lg[i] = v;
    mx = fmaxf(mx, v);
  }
  red[t] = mx;
  __syncthreads();
  for (int off = 128; off >= 1; off >>= 1) {
    if (t < off) red[t] = fmaxf(red[t], red[t + off]);
    __syncthreads();
  }
  const float m = red[0];
  __syncthreads();

  float zs = 0.f;
  for (int i = t; i < c0; i += 256) zs += expf(lg[i] - m);
  if (t == 0) zs += (float)(L_ - c0) * expf(-m);
  red[t] = zs;
  __syncthreads();
  for (int off = 128; off >= 1; off >>= 1) {
    if (t < off) red[t] += red[t + off];
    __syncthreads();
  }
  const float Z = red[0];
  __syncthreads();
  const float att0 = expf(-m) / Z;   // att value at every attended position

  for (int c = 0; c < C_; ++c) {
    const int st = starts[b * C_ + c];
    const int bound = (c < C_ - 1) ? (starts[b * C_ + c + 1] - 1) : (endv[b] - 1);
    const int lo = st + 1;
    const int hi = bound;
    float a = 0.f;
    for (int l = lo + t; l < hi; l += 256) a += d[(size_t)b * L_ + l];
    red[t] = a;
    __syncthreads();
    for (int off = 128; off >= 1; off >>= 1) {
      if (t < off) red[t] += red[t + off];
      __syncthreads();
    }
    if (t == 0) {
      int count = hi - lo;
      if (count < 0) count = 0;
      out[b * C_ + c] = red[0] + ws_scal[1] * att0 * (float)count + bcls[0];
    }
    __syncthreads();
  }
}

extern "C" void kernel_launch(void* const* d_in, const int* in_sizes, int n_in,
                              void* d_out, int out_size, void* d_ws, size_t ws_size,
                              hipStream_t stream) {
  const float* inp   = (const float*)d_in[0];
  const int*   attn  = (const int*)d_in[1];
  const int*   mlm   = (const int*)d_in[2];
  const float* Wh    = (const float*)d_in[3];
  const float* bh    = (const float*)d_in[4];
  const float* query = (const float*)d_in[5];
  const float* Wcls  = (const float*)d_in[6];
  const float* bcls  = (const float*)d_in[7];
  float* out = (float*)d_out;

  char* ws = (char*)d_ws;
  float*          ws_scal = (float*)(ws + OFF_SCAL);
  int*            endv    = (int*)(ws + OFF_END);
  int*            cnt     = (int*)(ws + OFF_CNT);
  int*            starts  = (int*)(ws + OFF_STARTS);
  int*            list    = (int*)(ws + OFF_LIST);
  unsigned short* W16     = (unsigned short*)(ws + OFF_W16);
  float*          probpart= (float*)(ws + OFF_PP);
  float*          dvec    = (float*)(ws + OFF_D);

  hipLaunchKernelGGL(kWA, dim3(B_ + 1 + KW_BLOCKS), dim3(256), 0, stream,
                     attn, mlm, query, Wcls, Wh, ws_scal, endv, cnt, starts, list, W16);
  hipLaunchKernelGGL(kMain, dim3(KC_BLOCKS + KE_BLOCKS), dim3(256), 0, stream,
                     inp, W16, bh, query, Wcls, attn, cnt, list, probpart, dvec);
  hipLaunchKernelGGL(kT, dim3(B_), dim3(256), 0, stream,
                     cnt, list, probpart, ws_scal, dvec, starts, endv, bcls, out);
}